// Round 13
// baseline (837.632 us; speedup 1.0000x reference)
//
#include <hip/hip_runtime.h>

typedef __attribute__((ext_vector_type(4))) float f32x4;
typedef __attribute__((ext_vector_type(8))) short short8;

#define D 128
#define D3 384
#define SLD 256   // S buffer row stride: [s | Vn]
#define EDIM 20
#define KPAD 32   // rbf K padded to 32 for MFMA
#define NR 3
#define NG 3
#define CUTOFF 5.0f
#define NNODES 10000
#define NEDGES 160000
#define NMOL 500
#define HROH 64
#define PI_F 3.14159265358979323846f

#define FBIAS 1
#define FSILU 2

static __device__ __forceinline__ float silu_f(float x) {
    return x / (1.0f + expf(-x));
}

// bf16 helpers (round-to-nearest-even)
static __device__ __forceinline__ ushort f2bf(float x) {
    uint u = __float_as_uint(x);
    uint r = (u + 0x7fffu + ((u >> 16) & 1u)) >> 16;
    return (ushort)r;
}
static __device__ __forceinline__ float bf2f(ushort h) {
    return __uint_as_float((uint)h << 16);
}
static __device__ __forceinline__ uint pack2(float a, float b) {
    return (uint)f2bf(a) | ((uint)f2bf(b) << 16);
}

#define TLR 64
#define TLC 64
#define KC 32
#define APAD 40
#define BPAD 36
#define CPAD 68   // f32 C-tile row stride (LDS bounce)

// ---------------------------------------------------------------------------
// wprep_k: one-time conversion of ALL weights to transposed [mat][M][K]
// hi/lo bf16. Segment table hardcoded; dst laid out linearly in seg order.
// ---------------------------------------------------------------------------
struct WSrc { const float* p[12]; };
#define WTOT 880640

__global__ __launch_bounds__(256) void wprep_k(WSrc ws, ushort* __restrict__ dh,
                                               ushort* __restrict__ dl)
{
    const int srcK[12] = {128,128, 20,128,128,256,128,128,128,256,128,128};
    const int dstK[12] = {128,128, 32,128,128,256,128,128,128,256,128,128};
    const int Mm[12]   = {128,384,384,128,128,128,384,128,128,128,256, 64};
    const int nm[12]   = {  3,  3,  3,  3,  3,  3,  3,  3,  3,  3,  3,  1};
    int i = blockIdx.x * 256 + threadIdx.x;
    if (i >= WTOT) return;
    int off = 0, seg = -1, loc = 0;
    #pragma unroll
    for (int s = 0; s < 12; ++s) {
        int sz = nm[s] * Mm[s] * dstK[s];
        if (seg < 0 && i < off + sz) { seg = s; loc = i - off; }
        off += sz;
    }
    int K = dstK[seg], M = Mm[seg], sK = srcK[seg];
    int mat = loc / (M * K);
    int rem = loc - mat * M * K;
    int m = rem / K, k = rem - m * K;
    float v = (k < sK) ? ws.p[seg][(size_t)(mat * sK + k) * M + m] : 0.f;
    ushort h = f2bf(v);
    dh[i] = h;
    dl[i] = f2bf(v - bf2f(h));
}

// segment element offsets (host-side constants, match wprep_k layout)
#define SEG_PHI_W1  0
#define SEG_PHI_W2  49152
#define SEG_FILT_W  196608
#define SEG_UPD_U   233472
#define SEG_UPD_V   282624
#define SEG_UPD_W1  331776
#define SEG_UPD_W2  430080
#define SEG_GEB_WV1 577536
#define SEG_GEB_WV2 626688
#define SEG_GEB_W1  675840
#define SEG_GEB_W2  774144
#define SEG_RO_W1   872448

// ---------------------------------------------------------------------------
// mlp_k<K1, M2, MODE>: out = silu(A@W1 + b1) @ W2 + b2, H kept in LDS.
// MODE 1: bf16 out (phi -> Pbf). MODE 2: update-apply epilogue
// (g0: s+=a_ss; g1: s+=a_sv*DOT; g2: v+=a_vv*Uv + bf16 mirror).
// MODE 3: geb-apply epilogue (g0: s=a; g1: v=gate*Uv + mirror).
// ---------------------------------------------------------------------------
template <int K1, int M2, int MODE>
__global__ __launch_bounds__(256) void mlp_k(
    const float* __restrict__ A, int lda,
    const ushort* __restrict__ W1h, const ushort* __restrict__ W1l,
    const float* __restrict__ b1,
    const ushort* __restrict__ W2h, const ushort* __restrict__ W2l,
    const float* __restrict__ b2,
    ushort* __restrict__ Cbf,
    float* __restrict__ SXp, const float* __restrict__ Uv,
    const float* __restrict__ DOT,
    float* __restrict__ V, ushort* __restrict__ Vbf, int N)
{
    __shared__ char SMB[27648 + 17408];
    ushort* Ah  = (ushort*)SMB;            // 32*40
    ushort* Al  = Ah + 1280;
    ushort* B1h = Ah + 2560;               // 128*36
    ushort* B1l = B1h + 4608;
    ushort* Hh  = (ushort*)(SMB + 27648);  // 32*136
    ushort* Hl  = Hh + 4352;

    const int tid = threadIdx.x;
    const int n0 = blockIdx.x * 32;
    const int w = tid >> 6;
    const int rt = w & 1;                  // row-tile (16 rows)
    const int ch = w >> 1;                 // col-half (64 cols)
    const int lane = tid & 63;
    const int fr = lane & 15;
    const int kg = lane >> 4;
    const int arow = tid & 31;
    const int akq = (tid >> 5) * 4;
    const bool aok = (n0 + arow) < N;
    const float* Ar = A + (size_t)(n0 + arow) * lda;
    const int bcol = tid & 127;
    const int bhalf = tid >> 7;            // 0/1 -> k-offset 0/16

    // ---------------- phase 1: H = silu(A@W1 + b1)
    f32x4 acc1[4];
    #pragma unroll
    for (int t = 0; t < 4; ++t) acc1[t] = (f32x4){0.f, 0.f, 0.f, 0.f};

    for (int k0 = 0; k0 < K1; k0 += KC) {
        {   // A stage (f32 -> hi/lo bf16)
            float4 v = aok ? *(const float4*)(Ar + k0 + akq)
                           : make_float4(0.f, 0.f, 0.f, 0.f);
            ushort h0 = f2bf(v.x), h1 = f2bf(v.y), h2 = f2bf(v.z), h3 = f2bf(v.w);
            ushort l0 = f2bf(v.x - bf2f(h0)), l1 = f2bf(v.y - bf2f(h1));
            ushort l2 = f2bf(v.z - bf2f(h2)), l3 = f2bf(v.w - bf2f(h3));
            uint2 ph, pl;
            ph.x = (uint)h0 | ((uint)h1 << 16); ph.y = (uint)h2 | ((uint)h3 << 16);
            pl.x = (uint)l0 | ((uint)l1 << 16); pl.y = (uint)l2 | ((uint)l3 << 16);
            *(uint2*)(Ah + arow * APAD + akq) = ph;
            *(uint2*)(Al + arow * APAD + akq) = pl;
        }
        {   // B1 stage: pure copy of 16 k's per thread
            const ushort* sh = W1h + (size_t)bcol * K1 + k0 + bhalf * 16;
            const ushort* sl = W1l + (size_t)bcol * K1 + k0 + bhalf * 16;
            ushort* dh = B1h + bcol * BPAD + bhalf * 16;
            ushort* dl = B1l + bcol * BPAD + bhalf * 16;
            uint4 v0 = *(const uint4*)sh;
            uint4 v1 = *(const uint4*)(sh + 8);
            *(uint2*)dh       = make_uint2(v0.x, v0.y);
            *(uint2*)(dh + 4) = make_uint2(v0.z, v0.w);
            *(uint2*)(dh + 8) = make_uint2(v1.x, v1.y);
            *(uint2*)(dh + 12)= make_uint2(v1.z, v1.w);
            uint4 u0 = *(const uint4*)sl;
            uint4 u1 = *(const uint4*)(sl + 8);
            *(uint2*)dl       = make_uint2(u0.x, u0.y);
            *(uint2*)(dl + 4) = make_uint2(u0.z, u0.w);
            *(uint2*)(dl + 8) = make_uint2(u1.x, u1.y);
            *(uint2*)(dl + 12)= make_uint2(u1.z, u1.w);
        }
        __syncthreads();
        short8 ah = *(const short8*)(Ah + (rt * 16 + fr) * APAD + kg * 8);
        short8 al = *(const short8*)(Al + (rt * 16 + fr) * APAD + kg * 8);
        #pragma unroll
        for (int t = 0; t < 4; ++t) {
            const ushort* bp = B1h + (ch * 64 + t * 16 + fr) * BPAD + kg * 8;
            const ushort* bq = B1l + (ch * 64 + t * 16 + fr) * BPAD + kg * 8;
            short8 bh, bl;
            ((uint2*)&bh)[0] = *(const uint2*)bp;
            ((uint2*)&bh)[1] = *(const uint2*)(bp + 4);
            ((uint2*)&bl)[0] = *(const uint2*)bq;
            ((uint2*)&bl)[1] = *(const uint2*)(bq + 4);
            acc1[t] = __builtin_amdgcn_mfma_f32_16x16x32_bf16(ah, bh, acc1[t], 0, 0, 0);
            acc1[t] = __builtin_amdgcn_mfma_f32_16x16x32_bf16(al, bh, acc1[t], 0, 0, 0);
            acc1[t] = __builtin_amdgcn_mfma_f32_16x16x32_bf16(ah, bl, acc1[t], 0, 0, 0);
        }
        __syncthreads();
    }
    // H -> LDS (bias + silu, split hi/lo)
    #pragma unroll
    for (int t = 0; t < 4; ++t) {
        int colm = ch * 64 + t * 16 + fr;
        float b = b1[colm];
        #pragma unroll
        for (int r = 0; r < 4; ++r) {
            int row = rt * 16 + kg * 4 + r;
            float hv = silu_f(acc1[t][r] + b);
            ushort hh = f2bf(hv);
            Hh[row * 136 + colm] = hh;
            Hl[row * 136 + colm] = f2bf(hv - bf2f(hh));
        }
    }
    __syncthreads();

    // ---------------- phase 2: out = H @ W2 + b2, per 128-col group
    ushort* B2h = (ushort*)SMB;            // reuse region0
    ushort* B2l = B2h + 4608;
    const int NG2 = M2 / 128;
    for (int g = 0; g < NG2; ++g) {
        f32x4 acc2[4];
        #pragma unroll
        for (int t = 0; t < 4; ++t) acc2[t] = (f32x4){0.f, 0.f, 0.f, 0.f};
        for (int k0 = 0; k0 < D; k0 += KC) {
            {   // B2 stage
                const ushort* sh = W2h + (size_t)(g * 128 + bcol) * D + k0 + bhalf * 16;
                const ushort* sl = W2l + (size_t)(g * 128 + bcol) * D + k0 + bhalf * 16;
                ushort* dh = B2h + bcol * BPAD + bhalf * 16;
                ushort* dl = B2l + bcol * BPAD + bhalf * 16;
                uint4 v0 = *(const uint4*)sh;
                uint4 v1 = *(const uint4*)(sh + 8);
                *(uint2*)dh       = make_uint2(v0.x, v0.y);
                *(uint2*)(dh + 4) = make_uint2(v0.z, v0.w);
                *(uint2*)(dh + 8) = make_uint2(v1.x, v1.y);
                *(uint2*)(dh + 12)= make_uint2(v1.z, v1.w);
                uint4 u0 = *(const uint4*)sl;
                uint4 u1 = *(const uint4*)(sl + 8);
                *(uint2*)dl       = make_uint2(u0.x, u0.y);
                *(uint2*)(dl + 4) = make_uint2(u0.z, u0.w);
                *(uint2*)(dl + 8) = make_uint2(u1.x, u1.y);
                *(uint2*)(dl + 12)= make_uint2(u1.z, u1.w);
            }
            __syncthreads();
            short8 ah, al;
            {
                const ushort* hp = Hh + (rt * 16 + fr) * 136 + k0 + kg * 8;
                const ushort* hq = Hl + (rt * 16 + fr) * 136 + k0 + kg * 8;
                ((uint2*)&ah)[0] = *(const uint2*)hp;
                ((uint2*)&ah)[1] = *(const uint2*)(hp + 4);
                ((uint2*)&al)[0] = *(const uint2*)hq;
                ((uint2*)&al)[1] = *(const uint2*)(hq + 4);
            }
            #pragma unroll
            for (int t = 0; t < 4; ++t) {
                const ushort* bp = B2h + (ch * 64 + t * 16 + fr) * BPAD + kg * 8;
                const ushort* bq = B2l + (ch * 64 + t * 16 + fr) * BPAD + kg * 8;
                short8 bh, bl;
                ((uint2*)&bh)[0] = *(const uint2*)bp;
                ((uint2*)&bh)[1] = *(const uint2*)(bp + 4);
                ((uint2*)&bl)[0] = *(const uint2*)bq;
                ((uint2*)&bl)[1] = *(const uint2*)(bq + 4);
                acc2[t] = __builtin_amdgcn_mfma_f32_16x16x32_bf16(ah, bh, acc2[t], 0, 0, 0);
                acc2[t] = __builtin_amdgcn_mfma_f32_16x16x32_bf16(al, bh, acc2[t], 0, 0, 0);
                acc2[t] = __builtin_amdgcn_mfma_f32_16x16x32_bf16(ah, bl, acc2[t], 0, 0, 0);
            }
            __syncthreads();
        }
        if (MODE == 1) {
            float* Cs = (float*)SMB;       // region0 (B2 dead)
            #pragma unroll
            for (int t = 0; t < 4; ++t) {
                int colm = ch * 64 + t * 16 + fr;
                float b = b2[g * 128 + colm];
                #pragma unroll
                for (int r = 0; r < 4; ++r) {
                    int row = rt * 16 + kg * 4 + r;
                    Cs[row * CPAD + colm] = acc2[t][r] + b;
                }
            }
            __syncthreads();
            #pragma unroll
            for (int it = 0; it < 2; ++it) {
                int chunk = it * 256 + tid;   // 512 = 32 rows x 16 octets
                int row = chunk >> 4;
                int c8 = (chunk & 15) * 8;
                int n = n0 + row;
                if (n < N) {
                    const float* src = Cs + row * CPAD + c8;
                    uint4 pk;
                    pk.x = pack2(src[0], src[1]);
                    pk.y = pack2(src[2], src[3]);
                    pk.z = pack2(src[4], src[5]);
                    pk.w = pack2(src[6], src[7]);
                    *(uint4*)(Cbf + (size_t)n * M2 + g * 128 + c8) = pk;
                }
            }
            __syncthreads();
        } else if (MODE == 2) {
            #pragma unroll
            for (int t = 0; t < 4; ++t) {
                int colm = ch * 64 + t * 16 + fr;   // 0..127 (= feature d)
                float b = b2[g * 128 + colm];
                #pragma unroll
                for (int r = 0; r < 4; ++r) {
                    int n = n0 + rt * 16 + kg * 4 + r;
                    if (n >= N) continue;
                    float val = acc2[t][r] + b;
                    if (g == 0) {
                        SXp[(size_t)n * SLD + colm] += val;
                    } else if (g == 1) {
                        SXp[(size_t)n * SLD + colm] +=
                            val * DOT[(size_t)n * D + colm];
                    } else {
                        const float* u = Uv + (size_t)n * D3 + colm;
                        float* vv = V + (size_t)n * D3 + colm;
                        ushort* vb = Vbf + (size_t)n * D3 + colm;
                        float nx = fmaf(val, u[0],     vv[0]);
                        float ny = fmaf(val, u[D],     vv[D]);
                        float nz = fmaf(val, u[2 * D], vv[2 * D]);
                        vv[0] = nx;     vb[0] = f2bf(nx);
                        vv[D] = ny;     vb[D] = f2bf(ny);
                        vv[2 * D] = nz; vb[2 * D] = f2bf(nz);
                    }
                }
            }
        } else {   // MODE == 3 (geb)
            #pragma unroll
            for (int t = 0; t < 4; ++t) {
                int colm = ch * 64 + t * 16 + fr;
                float b = b2[g * 128 + colm];
                #pragma unroll
                for (int r = 0; r < 4; ++r) {
                    int n = n0 + rt * 16 + kg * 4 + r;
                    if (n >= N) continue;
                    float val = acc2[t][r] + b;
                    if (g == 0) {
                        SXp[(size_t)n * SLD + colm] = val;
                    } else {
                        const float* u = Uv + (size_t)n * D3 + colm;
                        float* vv = V + (size_t)n * D3 + colm;
                        ushort* vb = Vbf + (size_t)n * D3 + colm;
                        float nx = val * u[0];
                        float ny = val * u[D];
                        float nz = val * u[2 * D];
                        vv[0] = nx;     vb[0] = f2bf(nx);
                        vv[D] = ny;     vb[D] = f2bf(ny);
                        vv[2 * D] = nz; vb[2 * D] = f2bf(nz);
                    }
                }
            }
        }
    }
}

// ---------------------------------------------------------------------------
// MFMA bf16x3 GEMM (readout only): C[n,m] = act(A@W + bias)
// ---------------------------------------------------------------------------
__global__ __launch_bounds__(256) void gemm_k(
    const float* __restrict__ A, int lda,
    const ushort* __restrict__ Wh, const ushort* __restrict__ Wl, int ldk,
    const float* __restrict__ bias,
    float* __restrict__ C, int ldc, int N, int K, int flags)
{
    const int n0 = blockIdx.x * TLR;
    const int m0 = blockIdx.y * TLC;
    __shared__ ushort SM[9728];
    ushort* Ah = SM;
    ushort* Al = SM + 2560;
    ushort* Bh = SM + 5120;
    ushort* Bl = SM + 7424;
    const int tid = threadIdx.x;
    const int arow = tid & 63;
    const int akq = (tid >> 6) * 4;
    const bool aok = (n0 + arow) < N;
    const float* Ar = A + (size_t)(n0 + arow) * lda;
    const int sm = tid & 63;
    const int sq = tid >> 6;
    const ushort* Wph = Wh + (size_t)(m0 + sm) * ldk + sq * 8;
    const ushort* Wpl = Wl + (size_t)(m0 + sm) * ldk + sq * 8;
    const int lane = tid & 63;
    const int wrow = (tid >> 6) * 16;
    const int fr = lane & 15;
    const int kg = lane >> 4;

    f32x4 acc[4];
    #pragma unroll
    for (int t = 0; t < 4; ++t) acc[t] = (f32x4){0.f, 0.f, 0.f, 0.f};

    for (int k0 = 0; k0 < K; k0 += KC) {
        #pragma unroll
        for (int half = 0; half < 2; ++half) {
            int kk = akq + half * 16;
            float4 v = aok ? *(const float4*)(Ar + k0 + kk)
                           : make_float4(0.f, 0.f, 0.f, 0.f);
            ushort h0 = f2bf(v.x), h1 = f2bf(v.y), h2 = f2bf(v.z), h3 = f2bf(v.w);
            ushort l0 = f2bf(v.x - bf2f(h0)), l1 = f2bf(v.y - bf2f(h1));
            ushort l2 = f2bf(v.z - bf2f(h2)), l3 = f2bf(v.w - bf2f(h3));
            uint2 ph, pl;
            ph.x = (uint)h0 | ((uint)h1 << 16); ph.y = (uint)h2 | ((uint)h3 << 16);
            pl.x = (uint)l0 | ((uint)l1 << 16); pl.y = (uint)l2 | ((uint)l3 << 16);
            *(uint2*)(Ah + arow * APAD + kk) = ph;
            *(uint2*)(Al + arow * APAD + kk) = pl;
        }
        {
            uint4 vh = *(const uint4*)(Wph + k0);
            uint4 vl = *(const uint4*)(Wpl + k0);
            ushort* dh = Bh + sm * BPAD + sq * 8;
            ushort* dl = Bl + sm * BPAD + sq * 8;
            *(uint2*)dh       = make_uint2(vh.x, vh.y);
            *(uint2*)(dh + 4) = make_uint2(vh.z, vh.w);
            *(uint2*)dl       = make_uint2(vl.x, vl.y);
            *(uint2*)(dl + 4) = make_uint2(vl.z, vl.w);
        }
        __syncthreads();
        short8 ah = *(const short8*)(Ah + (wrow + fr) * APAD + kg * 8);
        short8 al = *(const short8*)(Al + (wrow + fr) * APAD + kg * 8);
        #pragma unroll
        for (int t = 0; t < 4; ++t) {
            const ushort* bp = Bh + (t * 16 + fr) * BPAD + kg * 8;
            const ushort* bq = Bl + (t * 16 + fr) * BPAD + kg * 8;
            short8 bh, bl;
            ((uint2*)&bh)[0] = *(const uint2*)bp;
            ((uint2*)&bh)[1] = *(const uint2*)(bp + 4);
            ((uint2*)&bl)[0] = *(const uint2*)bq;
            ((uint2*)&bl)[1] = *(const uint2*)(bq + 4);
            acc[t] = __builtin_amdgcn_mfma_f32_16x16x32_bf16(ah, bh, acc[t], 0, 0, 0);
            acc[t] = __builtin_amdgcn_mfma_f32_16x16x32_bf16(al, bh, acc[t], 0, 0, 0);
            acc[t] = __builtin_amdgcn_mfma_f32_16x16x32_bf16(ah, bl, acc[t], 0, 0, 0);
        }
        __syncthreads();
    }

    #pragma unroll
    for (int t = 0; t < 4; ++t) {
        #pragma unroll
        for (int r = 0; r < 4; ++r) {
            int n = n0 + wrow + kg * 4 + r;
            if (n < N) {
                int m = m0 + t * 16 + fr;
                float val = acc[t][r];
                if (flags & FBIAS) val += bias[m];
                if (flags & FSILU) val = silu_f(val);
                C[(size_t)n * ldc + m] = val;
            }
        }
    }
}

// ---------------------------------------------------------------------------
// filt_k v2: X[e, 3D] = bf16( (rbf[e,:]@Wf + bf) * fcut[e] * phi[col_e] )
// Phi gathers PREFETCHED into registers before MFMA; Cs bounce ALIASES the
// dead A/B staging LDS (33 KB total -> 4 blocks/CU).
// ---------------------------------------------------------------------------
__global__ __launch_bounds__(256) void filt_k(
    const float* __restrict__ RBFp,
    const ushort* __restrict__ Wfh,
    const float* __restrict__ bias,
    const float* __restrict__ uf_s,
    const int* __restrict__ col_s,
    const ushort* __restrict__ Pbf,
    ushort* __restrict__ X, int E)
{
    __shared__ char SMB2[32768];         // union: Ah(5120)+Bs(27648) | Cs(17408)
    ushort* Ah = (ushort*)SMB2;
    ushort* Bs = (ushort*)(SMB2 + 5120);
    float*  Cs = (float*)SMB2;
    __shared__ int ColS[64];
    const int tid = threadIdx.x;
    const int e0 = blockIdx.x * 64;
    #pragma unroll
    for (int it = 0; it < 2; ++it) {
        int chunk = it * 256 + tid;
        int row = chunk >> 3;
        int kq = (chunk & 7) * 4;
        int e = e0 + row;
        float4 v = (e < E) ? *(const float4*)(RBFp + (size_t)e * KPAD + kq)
                           : make_float4(0.f, 0.f, 0.f, 0.f);
        uint2 ph;
        ph.x = pack2(v.x, v.y);
        ph.y = pack2(v.z, v.w);
        *(uint2*)(Ah + row * APAD + kq) = ph;
    }
    for (int m = tid; m < D3; m += 256) {
        const ushort* s = Wfh + (size_t)m * KPAD;
        ushort* dst = Bs + m * BPAD;
        #pragma unroll
        for (int q = 0; q < 2; ++q) {
            uint4 v = *(const uint4*)(s + q * 16);
            *(uint2*)(dst + q * 16)      = make_uint2(v.x, v.y);
            *(uint2*)(dst + q * 16 + 4)  = make_uint2(v.z, v.w);
            uint4 v2 = *(const uint4*)(s + q * 16 + 8);
            *(uint2*)(dst + q * 16 + 8)  = make_uint2(v2.x, v2.y);
            *(uint2*)(dst + q * 16 + 12) = make_uint2(v2.z, v2.w);
        }
    }
    if (tid < 64) {
        int e = e0 + tid;
        ColS[tid] = (e < E) ? col_s[e] : 0;
    }
    __syncthreads();

    // ---- prefetch phi for the pack phase: 12 uint4 into registers.
    // Chunk geometry (per bounce round ct, it in {0,1}): row/c8 independent
    // of ct; address = Pbf + ColS[row]*D3 + ct*64 + c8.
    const int prow0 = tid >> 3;              // it=0 row (0..31)
    const int prow1 = 32 + (tid >> 3);       // it=1 row (32..63)
    const int pc8 = (tid & 7) * 8;
    const bool p0ok = (e0 + prow0) < E;
    const bool p1ok = (e0 + prow1) < E;
    const ushort* pb0 = Pbf + (size_t)ColS[prow0] * D3 + pc8;
    const ushort* pb1 = Pbf + (size_t)ColS[prow1] * D3 + pc8;
    uint4 pg0[6], pg1[6];
    #pragma unroll
    for (int ct = 0; ct < 6; ++ct) {
        pg0[ct] = p0ok ? *(const uint4*)(pb0 + ct * 64) : make_uint4(0, 0, 0, 0);
        pg1[ct] = p1ok ? *(const uint4*)(pb1 + ct * 64) : make_uint4(0, 0, 0, 0);
    }

    const int lane = tid & 63;
    const int wrow = (tid >> 6) * 16;
    const int fr = lane & 15;
    const int kg = lane >> 4;
    short8 ah = *(const short8*)(Ah + (wrow + fr) * APAD + kg * 8);
    f32x4 acc[24];
    #pragma unroll
    for (int t = 0; t < 24; ++t) {
        const ushort* bp = Bs + (t * 16 + fr) * BPAD + kg * 8;
        short8 bh;
        ((uint2*)&bh)[0] = *(const uint2*)bp;
        ((uint2*)&bh)[1] = *(const uint2*)(bp + 4);
        acc[t] = __builtin_amdgcn_mfma_f32_16x16x32_bf16(
            ah, bh, (f32x4){0.f, 0.f, 0.f, 0.f}, 0, 0, 0);
    }
    float fc[4];
    #pragma unroll
    for (int r = 0; r < 4; ++r) {
        int e = e0 + wrow + kg * 4 + r;
        fc[r] = (e < E) ? uf_s[(size_t)e * 4 + 3] : 0.f;
    }
    for (int ct = 0; ct < 6; ++ct) {
        __syncthreads();    // at ct=0 this also retires all Ah/Bs reads
        #pragma unroll
        for (int tt = 0; tt < 4; ++tt) {
            int t = ct * 4 + tt;
            int colm = t * 16 + fr;
            float b = bias[colm];
            #pragma unroll
            for (int r = 0; r < 4; ++r) {
                int row = wrow + kg * 4 + r;
                Cs[row * CPAD + tt * 16 + fr] = (acc[t][r] + b) * fc[r];
            }
        }
        __syncthreads();
        #pragma unroll
        for (int it = 0; it < 2; ++it) {
            int row = it ? prow1 : prow0;
            int e = e0 + row;
            if (e < E) {
                int mbase = ct * 64 + pc8;
                uint4 pg = it ? pg1[ct] : pg0[ct];
                const float* src = Cs + row * CPAD + pc8;
                uint4 pk;
                pk.x = pack2(src[0] * bf2f((ushort)(pg.x & 0xffff)),
                             src[1] * bf2f((ushort)(pg.x >> 16)));
                pk.y = pack2(src[2] * bf2f((ushort)(pg.y & 0xffff)),
                             src[3] * bf2f((ushort)(pg.y >> 16)));
                pk.z = pack2(src[4] * bf2f((ushort)(pg.z & 0xffff)),
                             src[5] * bf2f((ushort)(pg.z >> 16)));
                pk.w = pack2(src[6] * bf2f((ushort)(pg.w & 0xffff)),
                             src[7] * bf2f((ushort)(pg.w >> 16)));
                *(uint4*)(X + (size_t)e * D3 + mbase) = pk;
            }
        }
    }
}

// ---------------------------------------------------------------------------
// uvn_k v3: A from bf16 V-mirror (pure copy stage, single-bf16 A-side ->
// 2 MFMA per cell instead of 3). Uv = v@WU, Vv = v@WV, Vn -> SX, DOT.
// ---------------------------------------------------------------------------
template <bool WITHDOT>
__global__ __launch_bounds__(256) void uvn_k(
    const ushort* __restrict__ Abf,   // [N][D3] bf16 v-mirror
    const ushort* __restrict__ WUh, const ushort* __restrict__ WUl,
    const ushort* __restrict__ WVh, const ushort* __restrict__ WVl,
    float* __restrict__ Uv,
    float* __restrict__ DOT,
    float* __restrict__ SX, int N)
{
    const int n0 = blockIdx.x * 32;
    const int m0 = blockIdx.y * 64;
    __shared__ ushort Ah[3][32 * APAD];
    __shared__ ushort Bh[2][64 * BPAD], Bl[2][64 * BPAD];
    const int tid = threadIdx.x;
    const int arow = tid & 31;
    const int akq = (tid >> 5) * 4;
    const bool aok = (n0 + arow) < N;
    const ushort* Ar = Abf + (size_t)(n0 + arow) * D3;
    const int sm = tid & 63;
    const int sq = tid >> 6;
    const int w = tid >> 6;
    const int rt = w & 1;
    const int ch = w >> 1;
    const int lane = tid & 63;
    const int fr = lane & 15;
    const int kg = lane >> 4;

    f32x4 acc[3][2][2];
    #pragma unroll
    for (int c = 0; c < 3; ++c)
        #pragma unroll
        for (int s = 0; s < 2; ++s)
            #pragma unroll
            for (int t = 0; t < 2; ++t) acc[c][s][t] = (f32x4){0.f, 0.f, 0.f, 0.f};

    for (int k0 = 0; k0 < D; k0 += KC) {
        #pragma unroll
        for (int c = 0; c < 3; ++c) {
            uint2 v = aok ? *(const uint2*)(Ar + c * D + k0 + akq)
                          : make_uint2(0, 0);
            *(uint2*)(&Ah[c][arow * APAD + akq]) = v;
        }
        #pragma unroll
        for (int s = 0; s < 2; ++s) {
            const ushort* sh = (s ? WVh : WUh) + (size_t)(m0 + sm) * D + k0 + sq * 8;
            const ushort* sl = (s ? WVl : WUl) + (size_t)(m0 + sm) * D + k0 + sq * 8;
            uint4 vh = *(const uint4*)sh;
            uint4 vl = *(const uint4*)sl;
            ushort* dh = &Bh[s][sm * BPAD + sq * 8];
            ushort* dl = &Bl[s][sm * BPAD + sq * 8];
            *(uint2*)dh       = make_uint2(vh.x, vh.y);
            *(uint2*)(dh + 4) = make_uint2(vh.z, vh.w);
            *(uint2*)dl       = make_uint2(vl.x, vl.y);
            *(uint2*)(dl + 4) = make_uint2(vl.z, vl.w);
        }
        __syncthreads();
        short8 ah[3];
        #pragma unroll
        for (int c = 0; c < 3; ++c)
            ah[c] = *(const short8*)(&Ah[c][(rt * 16 + fr) * APAD + kg * 8]);
        #pragma unroll
        for (int t = 0; t < 2; ++t) {
            #pragma unroll
            for (int s = 0; s < 2; ++s) {
                const ushort* bp = &Bh[s][(ch * 32 + t * 16 + fr) * BPAD + kg * 8];
                const ushort* bq = &Bl[s][(ch * 32 + t * 16 + fr) * BPAD + kg * 8];
                short8 bh, bl;
                ((uint2*)&bh)[0] = *(const uint2*)bp;
                ((uint2*)&bh)[1] = *(const uint2*)(bp + 4);
                ((uint2*)&bl)[0] = *(const uint2*)bq;
                ((uint2*)&bl)[1] = *(const uint2*)(bq + 4);
                #pragma unroll
                for (int c = 0; c < 3; ++c) {
                    acc[c][s][t] = __builtin_amdgcn_mfma_f32_16x16x32_bf16(ah[c], bh, acc[c][s][t], 0, 0, 0);
                    acc[c][s][t] = __builtin_amdgcn_mfma_f32_16x16x32_bf16(ah[c], bl, acc[c][s][t], 0, 0, 0);
                }
            }
        }
        __syncthreads();
    }
    #pragma unroll
    for (int t = 0; t < 2; ++t) {
        #pragma unroll
        for (int r = 0; r < 4; ++r) {
            int n = n0 + rt * 16 + kg * 4 + r;
            if (n < N) {
                int m = m0 + ch * 32 + t * 16 + fr;
                float ux = acc[0][0][t][r], uy = acc[1][0][t][r], uz = acc[2][0][t][r];
                float vx = acc[0][1][t][r], vy = acc[1][1][t][r], vz = acc[2][1][t][r];
                float* up = Uv + (size_t)n * D3 + m;
                up[0]     = ux;
                up[D]     = uy;
                up[2 * D] = uz;
                SX[(size_t)n * SLD + D + m] =
                    sqrtf(fmaf(vx, vx, fmaf(vy, vy, fmaf(vz, vz, 1e-8f))));
                if (WITHDOT)
                    DOT[(size_t)n * D + m] = fmaf(ux, vx, fmaf(uy, vy, uz * vz));
            }
        }
    }
}

// ---------------------------------------------------------------------------
__global__ __launch_bounds__(256) void emb_k(
    const float* __restrict__ h, const float* __restrict__ w,
    const float* __restrict__ b, float* __restrict__ s, int total)
{
    int i = blockIdx.x * 256 + threadIdx.x;
    if (i >= total) return;
    int n = i >> 7, d = i & 127;
    float acc = b[d];
    #pragma unroll
    for (int k = 0; k < 5; ++k) acc = fmaf(h[n * 5 + k], w[k * D + d], acc);
    s[(size_t)n * SLD + d] = acc;
}

__global__ __launch_bounds__(256) void hist_k(const int* __restrict__ ei,
                                              int* __restrict__ cnt, int E)
{
    int e = blockIdx.x * 256 + threadIdx.x;
    if (e < E) atomicAdd(&cnt[ei[e]], 1);
}

__global__ __launch_bounds__(256) void scan_k(const int* __restrict__ cnt,
                                              int* __restrict__ offs, int n)
{
    __shared__ int tmp[256];
    __shared__ int carry;
    if (threadIdx.x == 0) carry = 0;
    __syncthreads();
    for (int base = 0; base < n; base += 256) {
        int i = base + threadIdx.x;
        int v = (i < n) ? cnt[i] : 0;
        tmp[threadIdx.x] = v;
        __syncthreads();
        for (int off = 1; off < 256; off <<= 1) {
            int add = (threadIdx.x >= off) ? tmp[threadIdx.x - off] : 0;
            __syncthreads();
            tmp[threadIdx.x] += add;
            __syncthreads();
        }
        if (i < n) offs[i + 1] = carry + tmp[threadIdx.x];
        __syncthreads();
        if (threadIdx.x == 255) carry += tmp[255];
        __syncthreads();
    }
    if (threadIdx.x == 0) offs[0] = 0;
}

__global__ __launch_bounds__(256) void initnext_k(const int* __restrict__ offs,
                                                  int* __restrict__ next, int n)
{
    int i = blockIdx.x * 256 + threadIdx.x;
    if (i < n) next[i] = offs[i];
}

__global__ __launch_bounds__(256) void edge_pre_k(
    const int* __restrict__ ei, const float* __restrict__ pos,
    int* __restrict__ next, float* __restrict__ rbf_s,
    float* __restrict__ uf_s, int* __restrict__ col_s, int E)
{
    int e = blockIdx.x * 256 + threadIdx.x;
    if (e >= E) return;
    int r = ei[e], c = ei[E + e];
    float dx = pos[c * 3 + 0] - pos[r * 3 + 0];
    float dy = pos[c * 3 + 1] - pos[r * 3 + 1];
    float dz = pos[c * 3 + 2] - pos[r * 3 + 2];
    float dist = sqrtf(dx * dx + dy * dy + dz * dz);
    float d = fmaxf(dist, 1e-6f);
    float inv = 1.0f / d;
    int p = atomicAdd(&next[r], 1);
    col_s[p] = c;
    uf_s[p * 4 + 0] = dx * inv;
    uf_s[p * 4 + 1] = dy * inv;
    uf_s[p * 4 + 2] = dz * inv;
    uf_s[p * 4 + 3] = (d < CUTOFF) ? 0.5f * (cosf(PI_F * d / CUTOFF) + 1.0f) : 0.0f;
    float w = PI_F * d / CUTOFF;
    float* rb = rbf_s + (size_t)p * KPAD;
    #pragma unroll
    for (int k = 1; k <= EDIM; ++k)
        rb[k - 1] = sinf((float)k * w) * inv;
    #pragma unroll
    for (int k = EDIM; k < KPAD; ++k) rb[k] = 0.f;
}

// ---------------------------------------------------------------------------
// CSR message pass v7: one node per block, 2 groups x 128 lanes x 2-edge ILP
// (4 concurrent edge chains), LDS reduction of group partials.
// ---------------------------------------------------------------------------
__global__ __launch_bounds__(256) void message_csr_k(
    const int* __restrict__ offs, const int* __restrict__ col_s,
    const ushort* __restrict__ X, const float* __restrict__ uf_s,
    const float* __restrict__ Vold, const ushort* __restrict__ VbfOld,
    float* __restrict__ S, float* __restrict__ Vnew,
    ushort* __restrict__ VbfNew, int N)
{
    __shared__ float red[4][128];
    const int g = threadIdx.x >> 7;
    const int d = threadIdx.x & 127;
    const int n = blockIdx.x;

    auto edge = [&](int j, float& ds, float& dvx, float& dvy, float& dvz) {
        const ushort* xp = X + (size_t)j * D3;
        float xs  = bf2f(xp[d]);
        float xvv = bf2f(xp[D + d]);
        float xvw = bf2f(xp[2 * D + d]);
        int col = col_s[j];
        float4 u4 = *(const float4*)(uf_s + (size_t)j * 4);
        const ushort* vc = VbfOld + (size_t)col * D3;
        ds += xs;
        dvx = fmaf(xvv, bf2f(vc[d]),         fmaf(xvw, u4.x, dvx));
        dvy = fmaf(xvv, bf2f(vc[D + d]),     fmaf(xvw, u4.y, dvy));
        dvz = fmaf(xvv, bf2f(vc[2 * D + d]), fmaf(xvw, u4.z, dvz));
    };

    const int j0 = offs[n], j1 = offs[n + 1];
    const int half = (j1 - j0 + 1) >> 1;
    const int ja = g ? (j0 + half) : j0;
    const int jb = g ? j1 : (j0 + half);

    float ds0 = 0.f, dx0 = 0.f, dy0 = 0.f, dz0 = 0.f;
    float ds1 = 0.f, dx1 = 0.f, dy1 = 0.f, dz1 = 0.f;
    int j = ja;
    for (; j + 2 <= jb; j += 2) {
        edge(j, ds0, dx0, dy0, dz0);
        edge(j + 1, ds1, dx1, dy1, dz1);
    }
    if (j < jb) edge(j, ds0, dx0, dy0, dz0);
    ds0 += ds1; dx0 += dx1; dy0 += dy1; dz0 += dz1;

    if (g == 1) {
        red[0][d] = ds0; red[1][d] = dx0; red[2][d] = dy0; red[3][d] = dz0;
    }
    __syncthreads();
    if (g == 0) {
        ds0 += red[0][d]; dx0 += red[1][d]; dy0 += red[2][d]; dz0 += red[3][d];
        S[(size_t)n * SLD + d] += ds0;
        const float* vo = Vold + (size_t)n * D3;
        float* vn = Vnew + (size_t)n * D3;
        ushort* vb = VbfNew + (size_t)n * D3;
        float nx = vo[d] + dx0;
        float ny = vo[D + d] + dy0;
        float nz = vo[2 * D + d] + dz0;
        vn[d] = nx;         vb[d] = f2bf(nx);
        vn[D + d] = ny;     vb[D + d] = f2bf(ny);
        vn[2 * D + d] = nz; vb[2 * D + d] = f2bf(nz);
    }
}

__global__ __launch_bounds__(256) void readout_k(
    const float* __restrict__ H2, const float* __restrict__ w2,
    const float* __restrict__ b2, const int* __restrict__ batch,
    float* __restrict__ out, int N)
{
    int n = blockIdx.x * 256 + threadIdx.x;
    if (n >= N) return;
    float acc = b2[0];
    const float* hrow = H2 + (size_t)n * HROH;
    #pragma unroll
    for (int k = 0; k < HROH; ++k) acc = fmaf(hrow[k], w2[k], acc);
    atomicAdd(out + batch[n], acc);
}

// ---------------------------------------------------------------------------

extern "C" void kernel_launch(void* const* d_in, const int* in_sizes, int n_in,
                              void* d_out, int out_size, void* d_ws, size_t ws_size,
                              hipStream_t stream)
{
    const float* h          = (const float*)d_in[0];
    const float* pos        = (const float*)d_in[1];
    const int*   ei         = (const int*)d_in[2];
    const int*   batch      = (const int*)d_in[3];
    const float* emb_w      = (const float*)d_in[4];
    const float* emb_b      = (const float*)d_in[5];
    const float* msg_phi_w1 = (const float*)d_in[6];
    const float* msg_phi_b1 = (const float*)d_in[7];
    const float* msg_phi_w2 = (const float*)d_in[8];
    const float* msg_phi_b2 = (const float*)d_in[9];
    const float* msg_filt_w = (const float*)d_in[10];
    const float* msg_filt_b = (const float*)d_in[11];
    const float* upd_U      = (const float*)d_in[12];
    const float* upd_V      = (const float*)d_in[13];
    const float* upd_w1     = (const float*)d_in[14];
    const float* upd_b1     = (const float*)d_in[15];
    const float* upd_w2     = (const float*)d_in[16];
    const float* upd_b2     = (const float*)d_in[17];
    const float* geb_wv1    = (const float*)d_in[18];
    const float* geb_wv2    = (const float*)d_in[19];
    const float* geb_w1     = (const float*)d_in[20];
    const float* geb_b1     = (const float*)d_in[21];
    const float* geb_w2     = (const float*)d_in[22];
    const float* geb_b2     = (const float*)d_in[23];
    const float* ro_w1      = (const float*)d_in[24];
    const float* ro_b1      = (const float*)d_in[25];
    const float* ro_w2      = (const float*)d_in[26];
    const float* ro_b2      = (const float*)d_in[27];
    float* out = (float*)d_out;

    const int N = NNODES, E = NEDGES;

    char* p = (char*)d_ws;
    auto carve = [&](size_t bytes) {
        char* r = p;
        p += (bytes + 255) & ~(size_t)255;
        return r;
    };
    float*  SX   = (float*)carve((size_t)N * SLD * 4);   // [s | Vn]
    float*  VA   = (float*)carve((size_t)N * D3 * 4);
    float*  VB   = (float*)carve((size_t)N * D3 * 4);
    float*  P_   = (float*)carve((size_t)N * D3 * 4);    // Uv buffer / Pbf alias
    ushort* Pbf  = (ushort*)P_;
    ushort* VBFa = (ushort*)carve((size_t)N * D3 * 2);
    ushort* VBFb = (ushort*)carve((size_t)N * D3 * 2);
    float*  H    = (float*)carve((size_t)N * D * 4);     // DOT
    float*  H2   = (float*)carve((size_t)N * D * 4);     // readout hidden
    float*  RBFp = (float*)carve((size_t)E * KPAD * 4);
    float*  UFs  = (float*)carve((size_t)E * 4 * 4);
    int*    COLs = (int*)carve((size_t)E * 4);
    int*    offs = (int*)carve((size_t)(N + 1) * 4);
    int*    nxt  = (int*)carve((size_t)N * 4);
    ushort* WTH  = (ushort*)carve((size_t)WTOT * 2);
    ushort* WTL  = (ushort*)carve((size_t)WTOT * 2);
    ushort* X    = (ushort*)carve((size_t)E * D3 * 2);

    // one-time weight prep
    WSrc wsrc;
    wsrc.p[0] = msg_phi_w1; wsrc.p[1] = msg_phi_w2; wsrc.p[2] = msg_filt_w;
    wsrc.p[3] = upd_U;      wsrc.p[4] = upd_V;      wsrc.p[5] = upd_w1;
    wsrc.p[6] = upd_w2;     wsrc.p[7] = geb_wv1;    wsrc.p[8] = geb_wv2;
    wsrc.p[9] = geb_w1;     wsrc.p[10] = geb_w2;    wsrc.p[11] = ro_w1;
    hipLaunchKernelGGL(wprep_k, dim3((WTOT + 255) / 256), dim3(256), 0, stream,
                       wsrc, WTH, WTL);

    // init
    hipMemsetAsync(VA, 0, (size_t)N * D3 * 4, stream);
    hipMemsetAsync(VBFa, 0, (size_t)N * D3 * 2, stream);
    hipLaunchKernelGGL(emb_k, dim3((N * D + 255) / 256), dim3(256), 0, stream,
                       h, emb_w, emb_b, SX, N * D);
    hipMemsetAsync(nxt, 0, (size_t)N * 4, stream);
    hipLaunchKernelGGL(hist_k, dim3((E + 255) / 256), dim3(256), 0, stream, ei, nxt, E);
    hipLaunchKernelGGL(scan_k, dim3(1), dim3(256), 0, stream, nxt, offs, N);
    hipLaunchKernelGGL(initnext_k, dim3((N + 255) / 256), dim3(256), 0, stream,
                       offs, nxt, N);
    hipLaunchKernelGGL(edge_pre_k, dim3((E + 255) / 256), dim3(256), 0, stream,
                       ei, pos, nxt, RBFp, UFs, COLs, E);

    float*  Vc = VA;   ushort* VbfC = VBFa;
    float*  Vs = VB;   ushort* VbfS = VBFb;
    const int MB = (N + 31) / 32;

    for (int r = 0; r < NR; ++r) {
        // phi MLP fused -> bf16 P
        hipLaunchKernelGGL(HIP_KERNEL_NAME(mlp_k<128, 384, 1>),
                           dim3(MB), dim3(256), 0, stream,
                           SX, SLD,
                           WTH + SEG_PHI_W1 + (size_t)r * D * D,
                           WTL + SEG_PHI_W1 + (size_t)r * D * D,
                           msg_phi_b1 + (size_t)r * D,
                           WTH + SEG_PHI_W2 + (size_t)r * D * D3,
                           WTL + SEG_PHI_W2 + (size_t)r * D * D3,
                           msg_phi_b2 + (size_t)r * D3,
                           Pbf, nullptr, nullptr, nullptr, nullptr, nullptr, N);
        // X = (rbf@Wf + bf) * fcut * phi[col]
        hipLaunchKernelGGL(filt_k, dim3((E + 63) / 64), dim3(256), 0, stream,
                           RBFp, WTH + SEG_FILT_W + (size_t)r * KPAD * D3,
                           msg_filt_b + (size_t)r * D3, UFs, COLs, Pbf, X, E);
        // message: one node per block
        hipLaunchKernelGGL(message_csr_k, dim3(N), dim3(256), 0, stream,
                           offs, COLs, X, UFs, Vc, VbfC, SX, Vs, VbfS, N);
        { float* t = Vc; Vc = Vs; Vs = t; }
        { ushort* t = VbfC; VbfC = VbfS; VbfS = t; }
        float* Uv = Vs;
        // fused Uv/Vn/DOT (A from bf16 mirror)
        hipLaunchKernelGGL(HIP_KERNEL_NAME(uvn_k<true>),
                           dim3(MB, 2), dim3(256), 0, stream,
                           VbfC, WTH + SEG_UPD_U + (size_t)r * D * D,
                           WTL + SEG_UPD_U + (size_t)r * D * D,
                           WTH + SEG_UPD_V + (size_t)r * D * D,
                           WTL + SEG_UPD_V + (size_t)r * D * D,
                           Uv, H, SX, N);
        // update MLP fused with apply epilogue
        hipLaunchKernelGGL(HIP_KERNEL_NAME(mlp_k<256, 384, 2>),
                           dim3(MB), dim3(256), 0, stream,
                           SX, SLD,
                           WTH + SEG_UPD_W1 + (size_t)r * 2 * D * D,
                           WTL + SEG_UPD_W1 + (size_t)r * 2 * D * D,
                           upd_b1 + (size_t)r * D,
                           WTH + SEG_UPD_W2 + (size_t)r * D * D3,
                           WTL + SEG_UPD_W2 + (size_t)r * D * D3,
                           upd_b2 + (size_t)r * D3,
                           nullptr, SX, Uv, H, Vc, VbfC, N);
    }

    for (int g = 0; g < NG; ++g) {
        float* Uv = Vs;
        hipLaunchKernelGGL(HIP_KERNEL_NAME(uvn_k<false>),
                           dim3(MB, 2), dim3(256), 0, stream,
                           VbfC, WTH + SEG_GEB_WV1 + (size_t)g * D * D,
                           WTL + SEG_GEB_WV1 + (size_t)g * D * D,
                           WTH + SEG_GEB_WV2 + (size_t)g * D * D,
                           WTL + SEG_GEB_WV2 + (size_t)g * D * D,
                           Uv, nullptr, SX, N);
        hipLaunchKernelGGL(HIP_KERNEL_NAME(mlp_k<256, 256, 3>),
                           dim3(MB), dim3(256), 0, stream,
                           SX, SLD,
                           WTH + SEG_GEB_W1 + (size_t)g * 2 * D * D,
                           WTL + SEG_GEB_W1 + (size_t)g * 2 * D * D,
                           geb_b1 + (size_t)g * D,
                           WTH + SEG_GEB_W2 + (size_t)g * D * 2 * D,
                           WTL + SEG_GEB_W2 + (size_t)g * D * 2 * D,
                           geb_b2 + (size_t)g * 2 * D,
                           nullptr, SX, Uv, nullptr, Vc, VbfC, N);
    }

    // readout
    {
        dim3 grd((N + TLR - 1) / TLR, 1, 1);
        hipLaunchKernelGGL(gemm_k, grd, dim3(256), 0, stream,
                           SX, SLD, WTH + SEG_RO_W1, WTL + SEG_RO_W1, D,
                           ro_b1, H2, HROH, N, D, FBIAS | FSILU);
    }
    hipMemsetAsync(out, 0, (size_t)NMOL * 4, stream);
    hipLaunchKernelGGL(readout_k, dim3((N + 255) / 256), dim3(256), 0, stream,
                       H2, ro_w2, ro_b2, batch, out, N);
}

// Round 14
// 825.812 us; speedup vs baseline: 1.0143x; 1.0143x over previous
//
#include <hip/hip_runtime.h>

typedef __attribute__((ext_vector_type(4))) float f32x4;
typedef __attribute__((ext_vector_type(8))) short short8;

#define D 128
#define D3 384
#define SLD 256   // S buffer row stride: [s | Vn]
#define EDIM 20
#define KPAD 32   // rbf K padded to 32 for MFMA
#define NR 3
#define NG 3
#define CUTOFF 5.0f
#define NNODES 10000
#define NEDGES 160000
#define NMOL 500
#define HROH 64
#define PI_F 3.14159265358979323846f

#define FBIAS 1
#define FSILU 2

static __device__ __forceinline__ float silu_f(float x) {
    return x / (1.0f + expf(-x));
}

// bf16 helpers (round-to-nearest-even)
static __device__ __forceinline__ ushort f2bf(float x) {
    uint u = __float_as_uint(x);
    uint r = (u + 0x7fffu + ((u >> 16) & 1u)) >> 16;
    return (ushort)r;
}
static __device__ __forceinline__ float bf2f(ushort h) {
    return __uint_as_float((uint)h << 16);
}
static __device__ __forceinline__ uint pack2(float a, float b) {
    return (uint)f2bf(a) | ((uint)f2bf(b) << 16);
}

#define TLR 64
#define TLC 64
#define KC 32
#define APAD 40
#define BPAD 36
#define CPAD 68   // f32 C-tile row stride (LDS bounce)

// ---------------------------------------------------------------------------
// wprep_k: one-time conversion of ALL weights to transposed [mat][M][K]
// hi/lo bf16. Segment table hardcoded; dst laid out linearly in seg order.
// ---------------------------------------------------------------------------
struct WSrc { const float* p[12]; };
#define WTOT 880640

__global__ __launch_bounds__(256) void wprep_k(WSrc ws, ushort* __restrict__ dh,
                                               ushort* __restrict__ dl)
{
    const int srcK[12] = {128,128, 20,128,128,256,128,128,128,256,128,128};
    const int dstK[12] = {128,128, 32,128,128,256,128,128,128,256,128,128};
    const int Mm[12]   = {128,384,384,128,128,128,384,128,128,128,256, 64};
    const int nm[12]   = {  3,  3,  3,  3,  3,  3,  3,  3,  3,  3,  3,  1};
    int i = blockIdx.x * 256 + threadIdx.x;
    if (i >= WTOT) return;
    int off = 0, seg = -1, loc = 0;
    #pragma unroll
    for (int s = 0; s < 12; ++s) {
        int sz = nm[s] * Mm[s] * dstK[s];
        if (seg < 0 && i < off + sz) { seg = s; loc = i - off; }
        off += sz;
    }
    int K = dstK[seg], M = Mm[seg], sK = srcK[seg];
    int mat = loc / (M * K);
    int rem = loc - mat * M * K;
    int m = rem / K, k = rem - m * K;
    float v = (k < sK) ? ws.p[seg][(size_t)(mat * sK + k) * M + m] : 0.f;
    ushort h = f2bf(v);
    dh[i] = h;
    dl[i] = f2bf(v - bf2f(h));
}

// segment element offsets (host-side constants, match wprep_k layout)
#define SEG_PHI_W1  0
#define SEG_PHI_W2  49152
#define SEG_FILT_W  196608
#define SEG_UPD_U   233472
#define SEG_UPD_V   282624
#define SEG_UPD_W1  331776
#define SEG_UPD_W2  430080
#define SEG_GEB_WV1 577536
#define SEG_GEB_WV2 626688
#define SEG_GEB_W1  675840
#define SEG_GEB_W2  774144
#define SEG_RO_W1   872448

// ---------------------------------------------------------------------------
// mlp_k<K1, M2, MODE>: out = silu(A@W1 + b1) @ W2 + b2, H kept in LDS.
// MODE 1: bf16 out (phi -> Pbf). MODE 2: update-apply epilogue
// (g0: s+=a_ss; g1: s+=a_sv*DOT; g2: v+=a_vv*Uv + bf16 mirror).
// MODE 3: geb-apply epilogue (g0: s=a; g1: v=gate*Uv + mirror).
// ---------------------------------------------------------------------------
template <int K1, int M2, int MODE>
__global__ __launch_bounds__(256) void mlp_k(
    const float* __restrict__ A, int lda,
    const ushort* __restrict__ W1h, const ushort* __restrict__ W1l,
    const float* __restrict__ b1,
    const ushort* __restrict__ W2h, const ushort* __restrict__ W2l,
    const float* __restrict__ b2,
    ushort* __restrict__ Cbf,
    float* __restrict__ SXp, const float* __restrict__ Uv,
    const float* __restrict__ DOT,
    float* __restrict__ V, ushort* __restrict__ Vbf, int N)
{
    __shared__ char SMB[27648 + 17408];
    ushort* Ah  = (ushort*)SMB;            // 32*40
    ushort* Al  = Ah + 1280;
    ushort* B1h = Ah + 2560;               // 128*36
    ushort* B1l = B1h + 4608;
    ushort* Hh  = (ushort*)(SMB + 27648);  // 32*136
    ushort* Hl  = Hh + 4352;

    const int tid = threadIdx.x;
    const int n0 = blockIdx.x * 32;
    const int w = tid >> 6;
    const int rt = w & 1;                  // row-tile (16 rows)
    const int ch = w >> 1;                 // col-half (64 cols)
    const int lane = tid & 63;
    const int fr = lane & 15;
    const int kg = lane >> 4;
    const int arow = tid & 31;
    const int akq = (tid >> 5) * 4;
    const bool aok = (n0 + arow) < N;
    const float* Ar = A + (size_t)(n0 + arow) * lda;
    const int bcol = tid & 127;
    const int bhalf = tid >> 7;            // 0/1 -> k-offset 0/16

    // ---------------- phase 1: H = silu(A@W1 + b1)
    f32x4 acc1[4];
    #pragma unroll
    for (int t = 0; t < 4; ++t) acc1[t] = (f32x4){0.f, 0.f, 0.f, 0.f};

    for (int k0 = 0; k0 < K1; k0 += KC) {
        {   // A stage (f32 -> hi/lo bf16)
            float4 v = aok ? *(const float4*)(Ar + k0 + akq)
                           : make_float4(0.f, 0.f, 0.f, 0.f);
            ushort h0 = f2bf(v.x), h1 = f2bf(v.y), h2 = f2bf(v.z), h3 = f2bf(v.w);
            ushort l0 = f2bf(v.x - bf2f(h0)), l1 = f2bf(v.y - bf2f(h1));
            ushort l2 = f2bf(v.z - bf2f(h2)), l3 = f2bf(v.w - bf2f(h3));
            uint2 ph, pl;
            ph.x = (uint)h0 | ((uint)h1 << 16); ph.y = (uint)h2 | ((uint)h3 << 16);
            pl.x = (uint)l0 | ((uint)l1 << 16); pl.y = (uint)l2 | ((uint)l3 << 16);
            *(uint2*)(Ah + arow * APAD + akq) = ph;
            *(uint2*)(Al + arow * APAD + akq) = pl;
        }
        {   // B1 stage: pure copy of 16 k's per thread
            const ushort* sh = W1h + (size_t)bcol * K1 + k0 + bhalf * 16;
            const ushort* sl = W1l + (size_t)bcol * K1 + k0 + bhalf * 16;
            ushort* dh = B1h + bcol * BPAD + bhalf * 16;
            ushort* dl = B1l + bcol * BPAD + bhalf * 16;
            uint4 v0 = *(const uint4*)sh;
            uint4 v1 = *(const uint4*)(sh + 8);
            *(uint2*)dh       = make_uint2(v0.x, v0.y);
            *(uint2*)(dh + 4) = make_uint2(v0.z, v0.w);
            *(uint2*)(dh + 8) = make_uint2(v1.x, v1.y);
            *(uint2*)(dh + 12)= make_uint2(v1.z, v1.w);
            uint4 u0 = *(const uint4*)sl;
            uint4 u1 = *(const uint4*)(sl + 8);
            *(uint2*)dl       = make_uint2(u0.x, u0.y);
            *(uint2*)(dl + 4) = make_uint2(u0.z, u0.w);
            *(uint2*)(dl + 8) = make_uint2(u1.x, u1.y);
            *(uint2*)(dl + 12)= make_uint2(u1.z, u1.w);
        }
        __syncthreads();
        short8 ah = *(const short8*)(Ah + (rt * 16 + fr) * APAD + kg * 8);
        short8 al = *(const short8*)(Al + (rt * 16 + fr) * APAD + kg * 8);
        #pragma unroll
        for (int t = 0; t < 4; ++t) {
            const ushort* bp = B1h + (ch * 64 + t * 16 + fr) * BPAD + kg * 8;
            const ushort* bq = B1l + (ch * 64 + t * 16 + fr) * BPAD + kg * 8;
            short8 bh, bl;
            ((uint2*)&bh)[0] = *(const uint2*)bp;
            ((uint2*)&bh)[1] = *(const uint2*)(bp + 4);
            ((uint2*)&bl)[0] = *(const uint2*)bq;
            ((uint2*)&bl)[1] = *(const uint2*)(bq + 4);
            acc1[t] = __builtin_amdgcn_mfma_f32_16x16x32_bf16(ah, bh, acc1[t], 0, 0, 0);
            acc1[t] = __builtin_amdgcn_mfma_f32_16x16x32_bf16(al, bh, acc1[t], 0, 0, 0);
            acc1[t] = __builtin_amdgcn_mfma_f32_16x16x32_bf16(ah, bl, acc1[t], 0, 0, 0);
        }
        __syncthreads();
    }
    // H -> LDS (bias + silu, split hi/lo)
    #pragma unroll
    for (int t = 0; t < 4; ++t) {
        int colm = ch * 64 + t * 16 + fr;
        float b = b1[colm];
        #pragma unroll
        for (int r = 0; r < 4; ++r) {
            int row = rt * 16 + kg * 4 + r;
            float hv = silu_f(acc1[t][r] + b);
            ushort hh = f2bf(hv);
            Hh[row * 136 + colm] = hh;
            Hl[row * 136 + colm] = f2bf(hv - bf2f(hh));
        }
    }
    __syncthreads();

    // ---------------- phase 2: out = H @ W2 + b2, per 128-col group
    ushort* B2h = (ushort*)SMB;            // reuse region0
    ushort* B2l = B2h + 4608;
    const int NG2 = M2 / 128;
    for (int g = 0; g < NG2; ++g) {
        f32x4 acc2[4];
        #pragma unroll
        for (int t = 0; t < 4; ++t) acc2[t] = (f32x4){0.f, 0.f, 0.f, 0.f};
        for (int k0 = 0; k0 < D; k0 += KC) {
            {   // B2 stage
                const ushort* sh = W2h + (size_t)(g * 128 + bcol) * D + k0 + bhalf * 16;
                const ushort* sl = W2l + (size_t)(g * 128 + bcol) * D + k0 + bhalf * 16;
                ushort* dh = B2h + bcol * BPAD + bhalf * 16;
                ushort* dl = B2l + bcol * BPAD + bhalf * 16;
                uint4 v0 = *(const uint4*)sh;
                uint4 v1 = *(const uint4*)(sh + 8);
                *(uint2*)dh       = make_uint2(v0.x, v0.y);
                *(uint2*)(dh + 4) = make_uint2(v0.z, v0.w);
                *(uint2*)(dh + 8) = make_uint2(v1.x, v1.y);
                *(uint2*)(dh + 12)= make_uint2(v1.z, v1.w);
                uint4 u0 = *(const uint4*)sl;
                uint4 u1 = *(const uint4*)(sl + 8);
                *(uint2*)dl       = make_uint2(u0.x, u0.y);
                *(uint2*)(dl + 4) = make_uint2(u0.z, u0.w);
                *(uint2*)(dl + 8) = make_uint2(u1.x, u1.y);
                *(uint2*)(dl + 12)= make_uint2(u1.z, u1.w);
            }
            __syncthreads();
            short8 ah, al;
            {
                const ushort* hp = Hh + (rt * 16 + fr) * 136 + k0 + kg * 8;
                const ushort* hq = Hl + (rt * 16 + fr) * 136 + k0 + kg * 8;
                ((uint2*)&ah)[0] = *(const uint2*)hp;
                ((uint2*)&ah)[1] = *(const uint2*)(hp + 4);
                ((uint2*)&al)[0] = *(const uint2*)hq;
                ((uint2*)&al)[1] = *(const uint2*)(hq + 4);
            }
            #pragma unroll
            for (int t = 0; t < 4; ++t) {
                const ushort* bp = B2h + (ch * 64 + t * 16 + fr) * BPAD + kg * 8;
                const ushort* bq = B2l + (ch * 64 + t * 16 + fr) * BPAD + kg * 8;
                short8 bh, bl;
                ((uint2*)&bh)[0] = *(const uint2*)bp;
                ((uint2*)&bh)[1] = *(const uint2*)(bp + 4);
                ((uint2*)&bl)[0] = *(const uint2*)bq;
                ((uint2*)&bl)[1] = *(const uint2*)(bq + 4);
                acc2[t] = __builtin_amdgcn_mfma_f32_16x16x32_bf16(ah, bh, acc2[t], 0, 0, 0);
                acc2[t] = __builtin_amdgcn_mfma_f32_16x16x32_bf16(al, bh, acc2[t], 0, 0, 0);
                acc2[t] = __builtin_amdgcn_mfma_f32_16x16x32_bf16(ah, bl, acc2[t], 0, 0, 0);
            }
            __syncthreads();
        }
        if (MODE == 1) {
            float* Cs = (float*)SMB;       // region0 (B2 dead)
            #pragma unroll
            for (int t = 0; t < 4; ++t) {
                int colm = ch * 64 + t * 16 + fr;
                float b = b2[g * 128 + colm];
                #pragma unroll
                for (int r = 0; r < 4; ++r) {
                    int row = rt * 16 + kg * 4 + r;
                    Cs[row * CPAD + colm] = acc2[t][r] + b;
                }
            }
            __syncthreads();
            #pragma unroll
            for (int it = 0; it < 2; ++it) {
                int chunk = it * 256 + tid;   // 512 = 32 rows x 16 octets
                int row = chunk >> 4;
                int c8 = (chunk & 15) * 8;
                int n = n0 + row;
                if (n < N) {
                    const float* src = Cs + row * CPAD + c8;
                    uint4 pk;
                    pk.x = pack2(src[0], src[1]);
                    pk.y = pack2(src[2], src[3]);
                    pk.z = pack2(src[4], src[5]);
                    pk.w = pack2(src[6], src[7]);
                    *(uint4*)(Cbf + (size_t)n * M2 + g * 128 + c8) = pk;
                }
            }
            __syncthreads();
        } else if (MODE == 2) {
            #pragma unroll
            for (int t = 0; t < 4; ++t) {
                int colm = ch * 64 + t * 16 + fr;   // 0..127 (= feature d)
                float b = b2[g * 128 + colm];
                #pragma unroll
                for (int r = 0; r < 4; ++r) {
                    int n = n0 + rt * 16 + kg * 4 + r;
                    if (n >= N) continue;
                    float val = acc2[t][r] + b;
                    if (g == 0) {
                        SXp[(size_t)n * SLD + colm] += val;
                    } else if (g == 1) {
                        SXp[(size_t)n * SLD + colm] +=
                            val * DOT[(size_t)n * D + colm];
                    } else {
                        const float* u = Uv + (size_t)n * D3 + colm;
                        float* vv = V + (size_t)n * D3 + colm;
                        ushort* vb = Vbf + (size_t)n * D3 + colm;
                        float nx = fmaf(val, u[0],     vv[0]);
                        float ny = fmaf(val, u[D],     vv[D]);
                        float nz = fmaf(val, u[2 * D], vv[2 * D]);
                        vv[0] = nx;     vb[0] = f2bf(nx);
                        vv[D] = ny;     vb[D] = f2bf(ny);
                        vv[2 * D] = nz; vb[2 * D] = f2bf(nz);
                    }
                }
            }
        } else {   // MODE == 3 (geb)
            #pragma unroll
            for (int t = 0; t < 4; ++t) {
                int colm = ch * 64 + t * 16 + fr;
                float b = b2[g * 128 + colm];
                #pragma unroll
                for (int r = 0; r < 4; ++r) {
                    int n = n0 + rt * 16 + kg * 4 + r;
                    if (n >= N) continue;
                    float val = acc2[t][r] + b;
                    if (g == 0) {
                        SXp[(size_t)n * SLD + colm] = val;
                    } else {
                        const float* u = Uv + (size_t)n * D3 + colm;
                        float* vv = V + (size_t)n * D3 + colm;
                        ushort* vb = Vbf + (size_t)n * D3 + colm;
                        float nx = val * u[0];
                        float ny = val * u[D];
                        float nz = val * u[2 * D];
                        vv[0] = nx;     vb[0] = f2bf(nx);
                        vv[D] = ny;     vb[D] = f2bf(ny);
                        vv[2 * D] = nz; vb[2 * D] = f2bf(nz);
                    }
                }
            }
        }
    }
}

// ---------------------------------------------------------------------------
// MFMA bf16x3 GEMM (readout only): C[n,m] = act(A@W + bias)
// ---------------------------------------------------------------------------
__global__ __launch_bounds__(256) void gemm_k(
    const float* __restrict__ A, int lda,
    const ushort* __restrict__ Wh, const ushort* __restrict__ Wl, int ldk,
    const float* __restrict__ bias,
    float* __restrict__ C, int ldc, int N, int K, int flags)
{
    const int n0 = blockIdx.x * TLR;
    const int m0 = blockIdx.y * TLC;
    __shared__ ushort SM[9728];
    ushort* Ah = SM;
    ushort* Al = SM + 2560;
    ushort* Bh = SM + 5120;
    ushort* Bl = SM + 7424;
    const int tid = threadIdx.x;
    const int arow = tid & 63;
    const int akq = (tid >> 6) * 4;
    const bool aok = (n0 + arow) < N;
    const float* Ar = A + (size_t)(n0 + arow) * lda;
    const int sm = tid & 63;
    const int sq = tid >> 6;
    const ushort* Wph = Wh + (size_t)(m0 + sm) * ldk + sq * 8;
    const ushort* Wpl = Wl + (size_t)(m0 + sm) * ldk + sq * 8;
    const int lane = tid & 63;
    const int wrow = (tid >> 6) * 16;
    const int fr = lane & 15;
    const int kg = lane >> 4;

    f32x4 acc[4];
    #pragma unroll
    for (int t = 0; t < 4; ++t) acc[t] = (f32x4){0.f, 0.f, 0.f, 0.f};

    for (int k0 = 0; k0 < K; k0 += KC) {
        #pragma unroll
        for (int half = 0; half < 2; ++half) {
            int kk = akq + half * 16;
            float4 v = aok ? *(const float4*)(Ar + k0 + kk)
                           : make_float4(0.f, 0.f, 0.f, 0.f);
            ushort h0 = f2bf(v.x), h1 = f2bf(v.y), h2 = f2bf(v.z), h3 = f2bf(v.w);
            ushort l0 = f2bf(v.x - bf2f(h0)), l1 = f2bf(v.y - bf2f(h1));
            ushort l2 = f2bf(v.z - bf2f(h2)), l3 = f2bf(v.w - bf2f(h3));
            uint2 ph, pl;
            ph.x = (uint)h0 | ((uint)h1 << 16); ph.y = (uint)h2 | ((uint)h3 << 16);
            pl.x = (uint)l0 | ((uint)l1 << 16); pl.y = (uint)l2 | ((uint)l3 << 16);
            *(uint2*)(Ah + arow * APAD + kk) = ph;
            *(uint2*)(Al + arow * APAD + kk) = pl;
        }
        {
            uint4 vh = *(const uint4*)(Wph + k0);
            uint4 vl = *(const uint4*)(Wpl + k0);
            ushort* dh = Bh + sm * BPAD + sq * 8;
            ushort* dl = Bl + sm * BPAD + sq * 8;
            *(uint2*)dh       = make_uint2(vh.x, vh.y);
            *(uint2*)(dh + 4) = make_uint2(vh.z, vh.w);
            *(uint2*)dl       = make_uint2(vl.x, vl.y);
            *(uint2*)(dl + 4) = make_uint2(vl.z, vl.w);
        }
        __syncthreads();
        short8 ah = *(const short8*)(Ah + (wrow + fr) * APAD + kg * 8);
        short8 al = *(const short8*)(Al + (wrow + fr) * APAD + kg * 8);
        #pragma unroll
        for (int t = 0; t < 4; ++t) {
            const ushort* bp = Bh + (t * 16 + fr) * BPAD + kg * 8;
            const ushort* bq = Bl + (t * 16 + fr) * BPAD + kg * 8;
            short8 bh, bl;
            ((uint2*)&bh)[0] = *(const uint2*)bp;
            ((uint2*)&bh)[1] = *(const uint2*)(bp + 4);
            ((uint2*)&bl)[0] = *(const uint2*)bq;
            ((uint2*)&bl)[1] = *(const uint2*)(bq + 4);
            acc[t] = __builtin_amdgcn_mfma_f32_16x16x32_bf16(ah, bh, acc[t], 0, 0, 0);
            acc[t] = __builtin_amdgcn_mfma_f32_16x16x32_bf16(al, bh, acc[t], 0, 0, 0);
            acc[t] = __builtin_amdgcn_mfma_f32_16x16x32_bf16(ah, bl, acc[t], 0, 0, 0);
        }
        __syncthreads();
    }

    #pragma unroll
    for (int t = 0; t < 4; ++t) {
        #pragma unroll
        for (int r = 0; r < 4; ++r) {
            int n = n0 + wrow + kg * 4 + r;
            if (n < N) {
                int m = m0 + t * 16 + fr;
                float val = acc[t][r];
                if (flags & FBIAS) val += bias[m];
                if (flags & FSILU) val = silu_f(val);
                C[(size_t)n * ldc + m] = val;
            }
        }
    }
}

// ---------------------------------------------------------------------------
// filt_k v3: X[e, 3D] = bf16( (rbf[e,:]@Wf + bf) * fcut[e] * phi[col_e] )
// Gathers inline in pack phase (no register prefetch, 76 VGPR); Cs bounce
// aliases the dead Ah/Bs staging LDS (33 KB -> 4 blocks/CU).
// ---------------------------------------------------------------------------
__global__ __launch_bounds__(256) void filt_k(
    const float* __restrict__ RBFp,
    const ushort* __restrict__ Wfh,
    const float* __restrict__ bias,
    const float* __restrict__ uf_s,
    const int* __restrict__ col_s,
    const ushort* __restrict__ Pbf,
    ushort* __restrict__ X, int E)
{
    __shared__ char SMB2[32768];         // union: Ah(5120)+Bs(27648) | Cs(17408)
    ushort* Ah = (ushort*)SMB2;
    ushort* Bs = (ushort*)(SMB2 + 5120);
    float*  Cs = (float*)SMB2;
    __shared__ int ColS[64];
    const int tid = threadIdx.x;
    const int e0 = blockIdx.x * 64;
    #pragma unroll
    for (int it = 0; it < 2; ++it) {
        int chunk = it * 256 + tid;
        int row = chunk >> 3;
        int kq = (chunk & 7) * 4;
        int e = e0 + row;
        float4 v = (e < E) ? *(const float4*)(RBFp + (size_t)e * KPAD + kq)
                           : make_float4(0.f, 0.f, 0.f, 0.f);
        uint2 ph;
        ph.x = pack2(v.x, v.y);
        ph.y = pack2(v.z, v.w);
        *(uint2*)(Ah + row * APAD + kq) = ph;
    }
    for (int m = tid; m < D3; m += 256) {
        const ushort* s = Wfh + (size_t)m * KPAD;
        ushort* dst = Bs + m * BPAD;
        #pragma unroll
        for (int q = 0; q < 2; ++q) {
            uint4 v = *(const uint4*)(s + q * 16);
            *(uint2*)(dst + q * 16)      = make_uint2(v.x, v.y);
            *(uint2*)(dst + q * 16 + 4)  = make_uint2(v.z, v.w);
            uint4 v2 = *(const uint4*)(s + q * 16 + 8);
            *(uint2*)(dst + q * 16 + 8)  = make_uint2(v2.x, v2.y);
            *(uint2*)(dst + q * 16 + 12) = make_uint2(v2.z, v2.w);
        }
    }
    if (tid < 64) {
        int e = e0 + tid;
        ColS[tid] = (e < E) ? col_s[e] : 0;
    }
    __syncthreads();

    const int lane = tid & 63;
    const int wrow = (tid >> 6) * 16;
    const int fr = lane & 15;
    const int kg = lane >> 4;
    short8 ah = *(const short8*)(Ah + (wrow + fr) * APAD + kg * 8);
    f32x4 acc[24];
    #pragma unroll
    for (int t = 0; t < 24; ++t) {
        const ushort* bp = Bs + (t * 16 + fr) * BPAD + kg * 8;
        short8 bh;
        ((uint2*)&bh)[0] = *(const uint2*)bp;
        ((uint2*)&bh)[1] = *(const uint2*)(bp + 4);
        acc[t] = __builtin_amdgcn_mfma_f32_16x16x32_bf16(
            ah, bh, (f32x4){0.f, 0.f, 0.f, 0.f}, 0, 0, 0);
    }
    float fc[4];
    #pragma unroll
    for (int r = 0; r < 4; ++r) {
        int e = e0 + wrow + kg * 4 + r;
        fc[r] = (e < E) ? uf_s[(size_t)e * 4 + 3] : 0.f;
    }
    for (int ct = 0; ct < 6; ++ct) {
        __syncthreads();    // at ct=0 this also retires all Ah/Bs reads
        #pragma unroll
        for (int tt = 0; tt < 4; ++tt) {
            int t = ct * 4 + tt;
            int colm = t * 16 + fr;
            float b = bias[colm];
            #pragma unroll
            for (int r = 0; r < 4; ++r) {
                int row = wrow + kg * 4 + r;
                Cs[row * CPAD + tt * 16 + fr] = (acc[t][r] + b) * fc[r];
            }
        }
        __syncthreads();
        #pragma unroll
        for (int it = 0; it < 2; ++it) {
            int chunk = it * 256 + tid;
            int row = chunk >> 3;
            int c8 = (chunk & 7) * 8;
            int e = e0 + row;
            if (e < E) {
                int mbase = ct * 64 + c8;
                int col = ColS[row];
                uint4 pg = *(const uint4*)(Pbf + (size_t)col * D3 + mbase);
                const float* src = Cs + row * CPAD + c8;
                uint4 pk;
                pk.x = pack2(src[0] * bf2f((ushort)(pg.x & 0xffff)),
                             src[1] * bf2f((ushort)(pg.x >> 16)));
                pk.y = pack2(src[2] * bf2f((ushort)(pg.y & 0xffff)),
                             src[3] * bf2f((ushort)(pg.y >> 16)));
                pk.z = pack2(src[4] * bf2f((ushort)(pg.z & 0xffff)),
                             src[5] * bf2f((ushort)(pg.z >> 16)));
                pk.w = pack2(src[6] * bf2f((ushort)(pg.w & 0xffff)),
                             src[7] * bf2f((ushort)(pg.w >> 16)));
                *(uint4*)(X + (size_t)e * D3 + mbase) = pk;
            }
        }
    }
}

// ---------------------------------------------------------------------------
// uvn_k v3: A from bf16 V-mirror (pure copy stage, single-bf16 A-side ->
// 2 MFMA per cell instead of 3). Uv = v@WU, Vv = v@WV, Vn -> SX, DOT.
// ---------------------------------------------------------------------------
template <bool WITHDOT>
__global__ __launch_bounds__(256) void uvn_k(
    const ushort* __restrict__ Abf,   // [N][D3] bf16 v-mirror
    const ushort* __restrict__ WUh, const ushort* __restrict__ WUl,
    const ushort* __restrict__ WVh, const ushort* __restrict__ WVl,
    float* __restrict__ Uv,
    float* __restrict__ DOT,
    float* __restrict__ SX, int N)
{
    const int n0 = blockIdx.x * 32;
    const int m0 = blockIdx.y * 64;
    __shared__ ushort Ah[3][32 * APAD];
    __shared__ ushort Bh[2][64 * BPAD], Bl[2][64 * BPAD];
    const int tid = threadIdx.x;
    const int arow = tid & 31;
    const int akq = (tid >> 5) * 4;
    const bool aok = (n0 + arow) < N;
    const ushort* Ar = Abf + (size_t)(n0 + arow) * D3;
    const int sm = tid & 63;
    const int sq = tid >> 6;
    const int w = tid >> 6;
    const int rt = w & 1;
    const int ch = w >> 1;
    const int lane = tid & 63;
    const int fr = lane & 15;
    const int kg = lane >> 4;

    f32x4 acc[3][2][2];
    #pragma unroll
    for (int c = 0; c < 3; ++c)
        #pragma unroll
        for (int s = 0; s < 2; ++s)
            #pragma unroll
            for (int t = 0; t < 2; ++t) acc[c][s][t] = (f32x4){0.f, 0.f, 0.f, 0.f};

    for (int k0 = 0; k0 < D; k0 += KC) {
        #pragma unroll
        for (int c = 0; c < 3; ++c) {
            uint2 v = aok ? *(const uint2*)(Ar + c * D + k0 + akq)
                          : make_uint2(0, 0);
            *(uint2*)(&Ah[c][arow * APAD + akq]) = v;
        }
        #pragma unroll
        for (int s = 0; s < 2; ++s) {
            const ushort* sh = (s ? WVh : WUh) + (size_t)(m0 + sm) * D + k0 + sq * 8;
            const ushort* sl = (s ? WVl : WUl) + (size_t)(m0 + sm) * D + k0 + sq * 8;
            uint4 vh = *(const uint4*)sh;
            uint4 vl = *(const uint4*)sl;
            ushort* dh = &Bh[s][sm * BPAD + sq * 8];
            ushort* dl = &Bl[s][sm * BPAD + sq * 8];
            *(uint2*)dh       = make_uint2(vh.x, vh.y);
            *(uint2*)(dh + 4) = make_uint2(vh.z, vh.w);
            *(uint2*)dl       = make_uint2(vl.x, vl.y);
            *(uint2*)(dl + 4) = make_uint2(vl.z, vl.w);
        }
        __syncthreads();
        short8 ah[3];
        #pragma unroll
        for (int c = 0; c < 3; ++c)
            ah[c] = *(const short8*)(&Ah[c][(rt * 16 + fr) * APAD + kg * 8]);
        #pragma unroll
        for (int t = 0; t < 2; ++t) {
            #pragma unroll
            for (int s = 0; s < 2; ++s) {
                const ushort* bp = &Bh[s][(ch * 32 + t * 16 + fr) * BPAD + kg * 8];
                const ushort* bq = &Bl[s][(ch * 32 + t * 16 + fr) * BPAD + kg * 8];
                short8 bh, bl;
                ((uint2*)&bh)[0] = *(const uint2*)bp;
                ((uint2*)&bh)[1] = *(const uint2*)(bp + 4);
                ((uint2*)&bl)[0] = *(const uint2*)bq;
                ((uint2*)&bl)[1] = *(const uint2*)(bq + 4);
                #pragma unroll
                for (int c = 0; c < 3; ++c) {
                    acc[c][s][t] = __builtin_amdgcn_mfma_f32_16x16x32_bf16(ah[c], bh, acc[c][s][t], 0, 0, 0);
                    acc[c][s][t] = __builtin_amdgcn_mfma_f32_16x16x32_bf16(ah[c], bl, acc[c][s][t], 0, 0, 0);
                }
            }
        }
        __syncthreads();
    }
    #pragma unroll
    for (int t = 0; t < 2; ++t) {
        #pragma unroll
        for (int r = 0; r < 4; ++r) {
            int n = n0 + rt * 16 + kg * 4 + r;
            if (n < N) {
                int m = m0 + ch * 32 + t * 16 + fr;
                float ux = acc[0][0][t][r], uy = acc[1][0][t][r], uz = acc[2][0][t][r];
                float vx = acc[0][1][t][r], vy = acc[1][1][t][r], vz = acc[2][1][t][r];
                float* up = Uv + (size_t)n * D3 + m;
                up[0]     = ux;
                up[D]     = uy;
                up[2 * D] = uz;
                SX[(size_t)n * SLD + D + m] =
                    sqrtf(fmaf(vx, vx, fmaf(vy, vy, fmaf(vz, vz, 1e-8f))));
                if (WITHDOT)
                    DOT[(size_t)n * D + m] = fmaf(ux, vx, fmaf(uy, vy, uz * vz));
            }
        }
    }
}

// ---------------------------------------------------------------------------
__global__ __launch_bounds__(256) void emb_k(
    const float* __restrict__ h, const float* __restrict__ w,
    const float* __restrict__ b, float* __restrict__ s, int total)
{
    int i = blockIdx.x * 256 + threadIdx.x;
    if (i >= total) return;
    int n = i >> 7, d = i & 127;
    float acc = b[d];
    #pragma unroll
    for (int k = 0; k < 5; ++k) acc = fmaf(h[n * 5 + k], w[k * D + d], acc);
    s[(size_t)n * SLD + d] = acc;
}

__global__ __launch_bounds__(256) void hist_k(const int* __restrict__ ei,
                                              int* __restrict__ cnt, int E)
{
    int e = blockIdx.x * 256 + threadIdx.x;
    if (e < E) atomicAdd(&cnt[ei[e]], 1);
}

__global__ __launch_bounds__(256) void scan_k(const int* __restrict__ cnt,
                                              int* __restrict__ offs, int n)
{
    __shared__ int tmp[256];
    __shared__ int carry;
    if (threadIdx.x == 0) carry = 0;
    __syncthreads();
    for (int base = 0; base < n; base += 256) {
        int i = base + threadIdx.x;
        int v = (i < n) ? cnt[i] : 0;
        tmp[threadIdx.x] = v;
        __syncthreads();
        for (int off = 1; off < 256; off <<= 1) {
            int add = (threadIdx.x >= off) ? tmp[threadIdx.x - off] : 0;
            __syncthreads();
            tmp[threadIdx.x] += add;
            __syncthreads();
        }
        if (i < n) offs[i + 1] = carry + tmp[threadIdx.x];
        __syncthreads();
        if (threadIdx.x == 255) carry += tmp[255];
        __syncthreads();
    }
    if (threadIdx.x == 0) offs[0] = 0;
}

__global__ __launch_bounds__(256) void initnext_k(const int* __restrict__ offs,
                                                  int* __restrict__ next, int n)
{
    int i = blockIdx.x * 256 + threadIdx.x;
    if (i < n) next[i] = offs[i];
}

__global__ __launch_bounds__(256) void edge_pre_k(
    const int* __restrict__ ei, const float* __restrict__ pos,
    int* __restrict__ next, float* __restrict__ rbf_s,
    float* __restrict__ uf_s, int* __restrict__ col_s, int E)
{
    int e = blockIdx.x * 256 + threadIdx.x;
    if (e >= E) return;
    int r = ei[e], c = ei[E + e];
    float dx = pos[c * 3 + 0] - pos[r * 3 + 0];
    float dy = pos[c * 3 + 1] - pos[r * 3 + 1];
    float dz = pos[c * 3 + 2] - pos[r * 3 + 2];
    float dist = sqrtf(dx * dx + dy * dy + dz * dz);
    float d = fmaxf(dist, 1e-6f);
    float inv = 1.0f / d;
    int p = atomicAdd(&next[r], 1);
    col_s[p] = c;
    uf_s[p * 4 + 0] = dx * inv;
    uf_s[p * 4 + 1] = dy * inv;
    uf_s[p * 4 + 2] = dz * inv;
    uf_s[p * 4 + 3] = (d < CUTOFF) ? 0.5f * (cosf(PI_F * d / CUTOFF) + 1.0f) : 0.0f;
    float w = PI_F * d / CUTOFF;
    float* rb = rbf_s + (size_t)p * KPAD;
    #pragma unroll
    for (int k = 1; k <= EDIM; ++k)
        rb[k - 1] = sinf((float)k * w) * inv;
    #pragma unroll
    for (int k = EDIM; k < KPAD; ++k) rb[k] = 0.f;
}

// ---------------------------------------------------------------------------
// CSR message pass v7: one node per block, 2 groups x 128 lanes x 2-edge ILP
// (4 concurrent edge chains), LDS reduction of group partials.
// ---------------------------------------------------------------------------
__global__ __launch_bounds__(256) void message_csr_k(
    const int* __restrict__ offs, const int* __restrict__ col_s,
    const ushort* __restrict__ X, const float* __restrict__ uf_s,
    const float* __restrict__ Vold, const ushort* __restrict__ VbfOld,
    float* __restrict__ S, float* __restrict__ Vnew,
    ushort* __restrict__ VbfNew, int N)
{
    __shared__ float red[4][128];
    const int g = threadIdx.x >> 7;
    const int d = threadIdx.x & 127;
    const int n = blockIdx.x;

    auto edge = [&](int j, float& ds, float& dvx, float& dvy, float& dvz) {
        const ushort* xp = X + (size_t)j * D3;
        float xs  = bf2f(xp[d]);
        float xvv = bf2f(xp[D + d]);
        float xvw = bf2f(xp[2 * D + d]);
        int col = col_s[j];
        float4 u4 = *(const float4*)(uf_s + (size_t)j * 4);
        const ushort* vc = VbfOld + (size_t)col * D3;
        ds += xs;
        dvx = fmaf(xvv, bf2f(vc[d]),         fmaf(xvw, u4.x, dvx));
        dvy = fmaf(xvv, bf2f(vc[D + d]),     fmaf(xvw, u4.y, dvy));
        dvz = fmaf(xvv, bf2f(vc[2 * D + d]), fmaf(xvw, u4.z, dvz));
    };

    const int j0 = offs[n], j1 = offs[n + 1];
    const int half = (j1 - j0 + 1) >> 1;
    const int ja = g ? (j0 + half) : j0;
    const int jb = g ? j1 : (j0 + half);

    float ds0 = 0.f, dx0 = 0.f, dy0 = 0.f, dz0 = 0.f;
    float ds1 = 0.f, dx1 = 0.f, dy1 = 0.f, dz1 = 0.f;
    int j = ja;
    for (; j + 2 <= jb; j += 2) {
        edge(j, ds0, dx0, dy0, dz0);
        edge(j + 1, ds1, dx1, dy1, dz1);
    }
    if (j < jb) edge(j, ds0, dx0, dy0, dz0);
    ds0 += ds1; dx0 += dx1; dy0 += dy1; dz0 += dz1;

    if (g == 1) {
        red[0][d] = ds0; red[1][d] = dx0; red[2][d] = dy0; red[3][d] = dz0;
    }
    __syncthreads();
    if (g == 0) {
        ds0 += red[0][d]; dx0 += red[1][d]; dy0 += red[2][d]; dz0 += red[3][d];
        S[(size_t)n * SLD + d] += ds0;
        const float* vo = Vold + (size_t)n * D3;
        float* vn = Vnew + (size_t)n * D3;
        ushort* vb = VbfNew + (size_t)n * D3;
        float nx = vo[d] + dx0;
        float ny = vo[D + d] + dy0;
        float nz = vo[2 * D + d] + dz0;
        vn[d] = nx;         vb[d] = f2bf(nx);
        vn[D + d] = ny;     vb[D + d] = f2bf(ny);
        vn[2 * D + d] = nz; vb[2 * D + d] = f2bf(nz);
    }
}

__global__ __launch_bounds__(256) void readout_k(
    const float* __restrict__ H2, const float* __restrict__ w2,
    const float* __restrict__ b2, const int* __restrict__ batch,
    float* __restrict__ out, int N)
{
    int n = blockIdx.x * 256 + threadIdx.x;
    if (n >= N) return;
    float acc = b2[0];
    const float* hrow = H2 + (size_t)n * HROH;
    #pragma unroll
    for (int k = 0; k < HROH; ++k) acc = fmaf(hrow[k], w2[k], acc);
    atomicAdd(out + batch[n], acc);
}

// ---------------------------------------------------------------------------

extern "C" void kernel_launch(void* const* d_in, const int* in_sizes, int n_in,
                              void* d_out, int out_size, void* d_ws, size_t ws_size,
                              hipStream_t stream)
{
    const float* h          = (const float*)d_in[0];
    const float* pos        = (const float*)d_in[1];
    const int*   ei         = (const int*)d_in[2];
    const int*   batch      = (const int*)d_in[3];
    const float* emb_w      = (const float*)d_in[4];
    const float* emb_b      = (const float*)d_in[5];
    const float* msg_phi_w1 = (const float*)d_in[6];
    const float* msg_phi_b1 = (const float*)d_in[7];
    const float* msg_phi_w2 = (const float*)d_in[8];
    const float* msg_phi_b2 = (const float*)d_in[9];
    const float* msg_filt_w = (const float*)d_in[10];
    const float* msg_filt_b = (const float*)d_in[11];
    const float* upd_U      = (const float*)d_in[12];
    const float* upd_V      = (const float*)d_in[13];
    const float* upd_w1     = (const float*)d_in[14];
    const float* upd_b1     = (const float*)d_in[15];
    const float* upd_w2     = (const float*)d_in[16];
    const float* upd_b2     = (const float*)d_in[17];
    const float* geb_wv1    = (const float*)d_in[18];
    const float* geb_wv2    = (const float*)d_in[19];
    const float* geb_w1     = (const float*)d_in[20];
    const float* geb_b1     = (const float*)d_in[21];
    const float* geb_w2     = (const float*)d_in[22];
    const float* geb_b2     = (const float*)d_in[23];
    const float* ro_w1      = (const float*)d_in[24];
    const float* ro_b1      = (const float*)d_in[25];
    const float* ro_w2      = (const float*)d_in[26];
    const float* ro_b2      = (const float*)d_in[27];
    float* out = (float*)d_out;

    const int N = NNODES, E = NEDGES;

    char* p = (char*)d_ws;
    auto carve = [&](size_t bytes) {
        char* r = p;
        p += (bytes + 255) & ~(size_t)255;
        return r;
    };
    float*  SX   = (float*)carve((size_t)N * SLD * 4);   // [s | Vn]
    float*  VA   = (float*)carve((size_t)N * D3 * 4);
    float*  VB   = (float*)carve((size_t)N * D3 * 4);
    float*  P_   = (float*)carve((size_t)N * D3 * 4);    // Uv buffer / Pbf alias
    ushort* Pbf  = (ushort*)P_;
    ushort* VBFa = (ushort*)carve((size_t)N * D3 * 2);
    ushort* VBFb = (ushort*)carve((size_t)N * D3 * 2);
    float*  H    = (float*)carve((size_t)N * D * 4);     // DOT
    float*  H2   = (float*)carve((size_t)N * D * 4);     // readout hidden
    float*  RBFp = (float*)carve((size_t)E * KPAD * 4);
    float*  UFs  = (float*)carve((size_t)E * 4 * 4);
    int*    COLs = (int*)carve((size_t)E * 4);
    int*    offs = (int*)carve((size_t)(N + 1) * 4);
    int*    nxt  = (int*)carve((size_t)N * 4);
    ushort* WTH  = (ushort*)carve((size_t)WTOT * 2);
    ushort* WTL  = (ushort*)carve((size_t)WTOT * 2);
    ushort* X    = (ushort*)carve((size_t)E * D3 * 2);

    // one-time weight prep
    WSrc wsrc;
    wsrc.p[0] = msg_phi_w1; wsrc.p[1] = msg_phi_w2; wsrc.p[2] = msg_filt_w;
    wsrc.p[3] = upd_U;      wsrc.p[4] = upd_V;      wsrc.p[5] = upd_w1;
    wsrc.p[6] = upd_w2;     wsrc.p[7] = geb_wv1;    wsrc.p[8] = geb_wv2;
    wsrc.p[9] = geb_w1;     wsrc.p[10] = geb_w2;    wsrc.p[11] = ro_w1;
    hipLaunchKernelGGL(wprep_k, dim3((WTOT + 255) / 256), dim3(256), 0, stream,
                       wsrc, WTH, WTL);

    // init
    hipMemsetAsync(VA, 0, (size_t)N * D3 * 4, stream);
    hipMemsetAsync(VBFa, 0, (size_t)N * D3 * 2, stream);
    hipLaunchKernelGGL(emb_k, dim3((N * D + 255) / 256), dim3(256), 0, stream,
                       h, emb_w, emb_b, SX, N * D);
    hipMemsetAsync(nxt, 0, (size_t)N * 4, stream);
    hipLaunchKernelGGL(hist_k, dim3((E + 255) / 256), dim3(256), 0, stream, ei, nxt, E);
    hipLaunchKernelGGL(scan_k, dim3(1), dim3(256), 0, stream, nxt, offs, N);
    hipLaunchKernelGGL(initnext_k, dim3((N + 255) / 256), dim3(256), 0, stream,
                       offs, nxt, N);
    hipLaunchKernelGGL(edge_pre_k, dim3((E + 255) / 256), dim3(256), 0, stream,
                       ei, pos, nxt, RBFp, UFs, COLs, E);

    float*  Vc = VA;   ushort* VbfC = VBFa;
    float*  Vs = VB;   ushort* VbfS = VBFb;
    const int MB = (N + 31) / 32;

    for (int r = 0; r < NR; ++r) {
        // phi MLP fused -> bf16 P
        hipLaunchKernelGGL(HIP_KERNEL_NAME(mlp_k<128, 384, 1>),
                           dim3(MB), dim3(256), 0, stream,
                           SX, SLD,
                           WTH + SEG_PHI_W1 + (size_t)r * D * D,
                           WTL + SEG_PHI_W1 + (size_t)r * D * D,
                           msg_phi_b1 + (size_t)r * D,
                           WTH + SEG_PHI_W2 + (size_t)r * D * D3,
                           WTL + SEG_PHI_W2 + (size_t)r * D * D3,
                           msg_phi_b2 + (size_t)r * D3,
                           Pbf, nullptr, nullptr, nullptr, nullptr, nullptr, N);
        // X = (rbf@Wf + bf) * fcut * phi[col]
        hipLaunchKernelGGL(filt_k, dim3((E + 63) / 64), dim3(256), 0, stream,
                           RBFp, WTH + SEG_FILT_W + (size_t)r * KPAD * D3,
                           msg_filt_b + (size_t)r * D3, UFs, COLs, Pbf, X, E);
        // message: one node per block
        hipLaunchKernelGGL(message_csr_k, dim3(N), dim3(256), 0, stream,
                           offs, COLs, X, UFs, Vc, VbfC, SX, Vs, VbfS, N);
        { float* t = Vc; Vc = Vs; Vs = t; }
        { ushort* t = VbfC; VbfC = VbfS; VbfS = t; }
        float* Uv = Vs;
        // fused Uv/Vn/DOT (A from bf16 mirror)
        hipLaunchKernelGGL(HIP_KERNEL_NAME(uvn_k<true>),
                           dim3(MB, 2), dim3(256), 0, stream,
                           VbfC, WTH + SEG_UPD_U + (size_t)r * D * D,
                           WTL + SEG_UPD_U + (size_t)r * D * D,
                           WTH + SEG_UPD_V + (size_t)r * D * D,
                           WTL + SEG_UPD_V + (size_t)r * D * D,
                           Uv, H, SX, N);
        // update MLP fused with apply epilogue
        hipLaunchKernelGGL(HIP_KERNEL_NAME(mlp_k<256, 384, 2>),
                           dim3(MB), dim3(256), 0, stream,
                           SX, SLD,
                           WTH + SEG_UPD_W1 + (size_t)r * 2 * D * D,
                           WTL + SEG_UPD_W1 + (size_t)r * 2 * D * D,
                           upd_b1 + (size_t)r * D,
                           WTH + SEG_UPD_W2 + (size_t)r * D * D3,
                           WTL + SEG_UPD_W2 + (size_t)r * D * D3,
                           upd_b2 + (size_t)r * D3,
                           nullptr, SX, Uv, H, Vc, VbfC, N);
    }

    for (int g = 0; g < NG; ++g) {
        float* Uv = Vs;
        hipLaunchKernelGGL(HIP_KERNEL_NAME(uvn_k<false>),
                           dim3(MB, 2), dim3(256), 0, stream,
                           VbfC, WTH + SEG_GEB_WV1 + (size_t)g * D * D,
                           WTL + SEG_GEB_WV1 + (size_t)g * D * D,
                           WTH + SEG_GEB_WV2 + (size_t)g * D * D,
                           WTL + SEG_GEB_WV2 + (size_t)g * D * D,
                           Uv, nullptr, SX, N);
        hipLaunchKernelGGL(HIP_KERNEL_NAME(mlp_k<256, 256, 3>),
                           dim3(MB), dim3(256), 0, stream,
                           SX, SLD,
                           WTH + SEG_GEB_W1 + (size_t)g * 2 * D * D,
                           WTL + SEG_GEB_W1 + (size_t)g * 2 * D * D,
                           geb_b1 + (size_t)g * D,
                           WTH + SEG_GEB_W2 + (size_t)g * D * 2 * D,
                           WTL + SEG_GEB_W2 + (size_t)g * D * 2 * D,
                           geb_b2 + (size_t)g * 2 * D,
                           nullptr, SX, Uv, nullptr, Vc, VbfC, N);
    }

    // readout
    {
        dim3 grd((N + TLR - 1) / TLR, 1, 1);
        hipLaunchKernelGGL(gemm_k, grd, dim3(256), 0, stream,
                           SX, SLD, WTH + SEG_RO_W1, WTL + SEG_RO_W1, D,
                           ro_b1, H2, HROH, N, D, FBIAS | FSILU);
    }
    hipMemsetAsync(out, 0, (size_t)NMOL * 4, stream);
    hipLaunchKernelGGL(readout_k, dim3((N + 255) / 256), dim3(256), 0, stream,
                       H2, ro_w2, ro_b2, batch, out, N);
}